// Round 1
// baseline (172.803 us; speedup 1.0000x reference)
//
#include <hip/hip_runtime.h>
#include <math.h>

// WayfinderAttention: B=1, H=16, T=2048, DH=64, D=64 neighbors.
// One wave (64 lanes) per query. lane d owns neighbor d for the score phase;
// PV phase broadcasts (weight, idx) per valid neighbor and does coalesced
// 256B V-row loads. All gathers are L2-resident (per-head K+V = 1 MB).

#define T_DIM 2048
#define DH    64
#define NB    64
#define WAVES_PER_BLOCK 4

__global__ __launch_bounds__(WAVES_PER_BLOCK * 64)
void wayfinder_attn_kernel(const float* __restrict__ q,
                           const float* __restrict__ k,
                           const float* __restrict__ v,
                           const float* __restrict__ etb,   // 4 floats
                           const int*   __restrict__ neigh_idx,
                           const int*   __restrict__ edge_type,
                           float*       __restrict__ out)
{
    __shared__ float q_s[WAVES_PER_BLOCK][DH];

    const int lane = threadIdx.x & 63;
    const int wave = threadIdx.x >> 6;
    const int wq   = blockIdx.x * WAVES_PER_BLOCK + wave;   // flat h*T + t (B=1)
    const int t    = wq & (T_DIM - 1);
    const long long qbase    = (long long)wq * DH;
    const long long headbase = (long long)(wq - t) * DH;    // start of this head's K/V

    // stage q for this wave's query (256 B, coalesced)
    q_s[wave][lane] = q[qbase + lane];
    __syncthreads();

    // per-lane neighbor metadata (coalesced)
    const long long nbase = (long long)wq * NB;
    const int raw = neigh_idx[nbase + lane];
    const int et  = edge_type[nbase + lane];
    const bool valid = (raw >= 0) && (raw <= t);
    const int sj = min(max(raw, 0), T_DIM - 1);

    // score: dot(q, K[sj]) — per-lane contiguous 256 B row, 16x float4
    float dot = 0.f;
    if (valid) {
        const float4* __restrict__ krow = (const float4*)(k + headbase + (long long)sj * DH);
        const float4* __restrict__ qs4  = (const float4*)q_s[wave];
        #pragma unroll
        for (int i = 0; i < DH / 4; ++i) {
            float4 kv = krow[i];
            float4 qv = qs4[i];
            dot += kv.x * qv.x + kv.y * qv.y + kv.z * qv.z + kv.w * qv.w;
        }
    }
    float bias  = (et != 0) ? etb[et - 1] : 0.f;
    float score = valid ? (dot * 0.125f + bias) : -INFINITY;

    // wave-wide masked softmax (64-lane shuffle reductions)
    float m = score;
    #pragma unroll
    for (int o = 32; o > 0; o >>= 1) m = fmaxf(m, __shfl_xor(m, o, 64));
    float e = valid ? __expf(score - m) : 0.f;
    float s = e;
    #pragma unroll
    for (int o = 32; o > 0; o >>= 1) s += __shfl_xor(s, o, 64);
    const float w = e / fmaxf(s, 1e-20f);

    // PV: iterate only valid neighbors (w==0 for invalid -> exact skip);
    // each iteration is a coalesced 256 B V-row load.
    float acc = 0.f;
    unsigned long long vb = __ballot(valid);
    const float* __restrict__ vhead = v + headbase;
    while (vb) {
        const int d = __builtin_ctzll(vb);
        vb &= vb - 1;
        const float wd = __shfl(w, d, 64);
        const int   jd = __shfl(sj, d, 64);
        acc += wd * vhead[jd * DH + lane];
    }
    out[qbase + lane] = acc;
}

extern "C" void kernel_launch(void* const* d_in, const int* in_sizes, int n_in,
                              void* d_out, int out_size, void* d_ws, size_t ws_size,
                              hipStream_t stream)
{
    const float* q   = (const float*)d_in[0];
    const float* k   = (const float*)d_in[1];
    const float* v   = (const float*)d_in[2];
    const float* etb = (const float*)d_in[3];
    const int* neigh_idx = (const int*)d_in[4];
    const int* edge_type = (const int*)d_in[5];
    float* out = (float*)d_out;

    const int total_queries = 16 * T_DIM;                 // B*H*T = 32768
    const int blocks = total_queries / WAVES_PER_BLOCK;   // 8192
    hipLaunchKernelGGL(wayfinder_attn_kernel, dim3(blocks), dim3(WAVES_PER_BLOCK * 64),
                       0, stream, q, k, v, etb, neigh_idx, edge_type, out);
}